// Round 17
// baseline (73.117 us; speedup 1.0000x reference)
//
#include <hip/hip_runtime.h>
#include <hip/hip_bf16.h>
#include <math.h>

// Shapes: B=32, C=128, O=128, K=3, L=4096, W=1, PAD=1, DIL=1
// out[b,o,i] = sum_kc Wr[kc,o] * G[b,kc,i],  kc = k*128+c (K=384)
// G[b,kc,i] = wae[b,k,i]*x[b,c,addr] + wbe[b,k,i]*x[b,c,addr+1]
//
// r17 = r16 + 32x32x16 MFMA: block = 4 o-tiles x 4 i-tiles (32x32);
// wave = (o-tile w>>1, i-half w&1) -> 2 tiles, acc 2 x f32x16 (32 VGPR, same).
// B-frag shared by 4 (not 8) waves; consumer ds_read_b128 halved (192->96
// per block-phase) -- the invariant ~40us LDS term across r12/r14/r16.
// Producer: wave w = (i-tile w>>1, channel-half w&1), interp unchanged.
// Layouts: A row=l&31,k=(l>>5)*8+e; B col=l&31,k=(l>>5)*8+e;
// C/D col=lane&31,row=(reg&3)+8*(reg>>2)+4*(lane>>5)  [m74/m101].
//
// ws layout (bytes):
//   WrA @ 0       : bf16 A-frags (32x32), 4 ot x 24 sg x 64 x 16B = 98304
//   wT  @ 98304   : float[128*32] transposed conv weights
//   addr2 @ 131072: int[32*3*4096]
//   wae @ 1703936 : float[32*3*4096]
//   wbe @ 3276800 : float[32*3*4096]

typedef __attribute__((ext_vector_type(8)))  short bf16x8;
typedef __attribute__((ext_vector_type(4)))  float f32x4;
typedef __attribute__((ext_vector_type(16))) float f32x16;
typedef float f32x2u __attribute__((ext_vector_type(2), aligned(4)));

#define WIN 160
#define WP32 162   // u32 row stride: even (b64-aligned), bank shift 2/row

static __device__ inline unsigned short f2bf(float f) {
    __hip_bfloat16 h = __float2bfloat16(f);
    union { __hip_bfloat16 b; unsigned short u; } cv;
    cv.b = h;
    return cv.u;
}
static __device__ inline unsigned pk2(float a, float b) {
    return (unsigned)f2bf(a) | ((unsigned)f2bf(b) << 16);
}

// ---------- kernel 0: pack WrA (32x32 A-frags) + wT (conv weights) ----------
// A-frag (ot, sg), lane l, elem e: A[o = ot*32+(l&31)][kc = sg*16+(l>>5)*8+e]
__global__ __launch_bounds__(256) void k_wra(const float* __restrict__ w_reg,
                                             const float* __restrict__ w_off,
                                             const float* __restrict__ w_mod,
                                             unsigned short* __restrict__ WrA,
                                             float* __restrict__ wT) {
    int t = blockIdx.x * 256 + threadIdx.x;
    if (t < 49152) {
        int e  = t & 7;
        int l  = (t >> 3) & 63;
        int os = t >> 9;              // ot*24 + sg
        int ot = os / 24;
        int sg = os - ot * 24;
        int o  = ot * 32 + (l & 31);
        int kc = sg * 16 + ((l >> 5) & 1) * 8 + e;
        int tap = kc >> 7;
        int c   = kc & 127;
        WrA[t] = f2bf(w_reg[(o * 128 + c) * 3 + tap]);
    } else if (t < 49152 + 128 * 27) {
        int u = t - 49152;
        int c = u / 27, r = u - c * 27;
        int ch = r / 3, tap = r - ch * 3;
        wT[c * 32 + r] = (ch < 6) ? w_off[(ch * 128 + c) * 3 + tap]
                                  : w_mod[((ch - 6) * 128 + c) * 3 + tap];
    }
}

// ---------- kernel 1: offset/mask conv, 8 waves x 16 channels (r9 exact) ----------
__global__ __launch_bounds__(512) void k_prep(const float* __restrict__ x,
                                              const float* __restrict__ wT,
                                              const float* __restrict__ b_off,
                                              const float* __restrict__ b_mod,
                                              int* __restrict__ addr2,
                                              float* __restrict__ wae,
                                              float* __restrict__ wbe) {
    __shared__ float red[7 * 64 * 19];            // 34 KB, stride 19 (odd)
    int t = threadIdx.x;
    int lane = t & 63;
    int wv = t >> 6;                              // 0..7
    int b = blockIdx.y;
    int i = blockIdx.x * 128 + lane * 2;          // lane covers i, i+1

    int c0 = __builtin_amdgcn_readfirstlane(wv) * 16;

    float acc[18];
#pragma unroll
    for (int z = 0; z < 18; ++z) acc[z] = 0.f;

    const float* xr = x + (size_t)b * 524288 + (size_t)c0 * 4096;
    const float* wbase = wT + c0 * 32;
#pragma unroll 2
    for (int c = 0; c < 16; ++c) {
        const float* row = xr + (size_t)c * 4096;
        f32x2u v = *(const f32x2u*)(row + i);
        float lm = row[max(i - 1, 0)];
        float rp = row[min(i + 2, 4095)];
        float left  = (i > 0)        ? lm : 0.f;
        float right = (i + 2 < 4096) ? rp : 0.f;
        const float* wrow = wbase + c * 32;       // wave-uniform -> s_load
#pragma unroll
        for (int ch = 0; ch < 9; ++ch) {
            float w0 = wrow[ch * 3 + 0];
            float w1 = wrow[ch * 3 + 1];
            float w2 = wrow[ch * 3 + 2];
            acc[ch * 2 + 0] += left * w0 + v.x * w1 + v.y  * w2;
            acc[ch * 2 + 1] += v.x  * w0 + v.y * w1 + right * w2;
        }
    }

    if (wv > 0) {
        float* r = &red[((wv - 1) * 64 + lane) * 19];
#pragma unroll
        for (int z = 0; z < 18; ++z) r[z] = acc[z];
    }
    __syncthreads();
    if (wv != 0) return;

#pragma unroll
    for (int p = 0; p < 7; ++p) {
        const float* r = &red[(p * 64 + lane) * 19];
#pragma unroll
        for (int z = 0; z < 18; ++z) acc[z] += r[z];
    }

#pragma unroll
    for (int k = 0; k < 3; ++k) {
        int   av[2];
        float wav[2], wbv[2];
#pragma unroll
        for (int ii = 0; ii < 2; ++ii) {
            float offy = acc[(2 * k) * 2 + ii]     + b_off[2 * k];
            float offx = acc[(2 * k + 1) * 2 + ii] + b_off[2 * k + 1];
            offy = fminf(fmaxf(offy, -1024.f), 1024.f);
            offx = fminf(fmaxf(offx, -1024.f), 1024.f);
            float am = acc[(6 + k) * 2 + ii] + b_mod[k];
            float m  = 2.f / (1.f + expf(-am));

            float py = (float)(i + ii - 1 + k) + offy;
            float y0 = floorf(py);
            int   iy0 = (int)y0;
            float wy1 = py - y0, wy0 = 1.f - wy1;
            float x0f = floorf(offx);
            int   ix0 = (int)x0f;
            float wx1 = offx - x0f, wx0 = 1.f - wx1;

            float sx = (ix0 == 0) ? wx0 : ((ix0 == -1) ? wx1 : 0.f);
            float scal = m * sx;

            float wAv = (iy0 >= 0 && iy0 < 4096)  ? scal * wy0 : 0.f;
            float wBv = (iy0 >= -1 && iy0 < 4095) ? scal * wy1 : 0.f;

            int addr = min(max(iy0, 0), 4094);
            bool eq = (iy0 == addr);
            wav[ii] = eq ? wAv : (iy0 == -1   ? wBv : 0.f);
            wbv[ii] = eq ? wBv : (iy0 == 4095 ? wAv : 0.f);
            av[ii] = addr;
        }
        int j = (b * 3 + k) * 4096 + i;
        *(int2*)(addr2 + j)  = make_int2(av[0], av[1]);
        *(f32x2u*)(wae + j)  = (f32x2u){wav[0], wav[1]};
        *(f32x2u*)(wbe + j)  = (f32x2u){wbv[0], wbv[1]};
    }
}

// ---------- kernel 2: fused gather + 32x32x16 MFMA GEMM ----------
// grid (32 i-tiles, 32 b), 512 threads = 8 waves. Block: 128 i x 128 o.
// Producer: wave w = (i-tile w>>1, ch-half w&1) -> Bl[it][tap*2+h].
// Consumer: wave w = (o-tile w>>1, i-half w&1) -> 2 tiles, acc 2 x f32x16.
__global__ __launch_bounds__(512) void k_fused(const unsigned short* __restrict__ WrA,
                                               const float* __restrict__ x,
                                               const int* __restrict__ addr2,
                                               const float* __restrict__ wae,
                                               const float* __restrict__ wbe,
                                               float* __restrict__ out) {
    __shared__ unsigned win32[32 * WP32];          // 20.7 KB packed bf16 pairs
    __shared__ short Bl[4][6][512];                // 24 KB single buffer
    int t = threadIdx.x;
    int l = t & 63;
    int w = t >> 6;                                // 0..7
    int b  = blockIdx.y;
    int ib = blockIdx.x;
    int cl = l & 31;
    int eh = (l >> 5) & 1;
    int i0t = ib * 128;
    int itp = w >> 1;                              // producer i-tile
    int hp  = w & 1;                               // producer channel-half
    int ot  = w >> 1;                              // consumer o-tile
    int ih  = w & 1;                               // consumer i-half
    int i0p = i0t + itp * 32 + cl;                 // producer's i
    int wsod = i0t - 16;
    if (wsod > 4096 - WIN) wsod = 4096 - WIN;
    if (wsod < 0) wsod = 0;
    const float* xb = x + (size_t)b * 524288;
    const bf16x8* Ag = (const bf16x8*)WrA;

    // producer gather params + wave-uniform in-window flags
    int   a_[3];
    float wa_[3], wb_[3];
    bool  okw[3];
#pragma unroll
    for (int k = 0; k < 3; ++k) {
        int j = (b * 3 + k) * 4096 + i0p;
        int a = addr2[j];
        a_[k]  = a;
        wa_[k] = wae[j];
        wb_[k] = wbe[j];
        okw[k] = (bool)__all(a >= wsod && a <= wsod + WIN - 2);
    }

    f32x16 acc[2];
#pragma unroll
    for (int j = 0; j < 2; ++j)
#pragma unroll
        for (int r = 0; r < 16; ++r) acc[j][r] = 0.f;

    // prologue: load + pack + write window for cc=0
#pragma unroll
    for (int it = 0; it < 3; ++it) {
        int idx = it * 512 + t;
        if (idx < 1280) {
            int r = idx / 40, cp = idx - r * 40;
            const float* row = xb + (size_t)r * 4096;
            int c0 = wsod + cp * 4;
            float4 v = *(const float4*)(row + c0);
            float nx = row[min(c0 + 4, 4095)];
            unsigned* d = &win32[r * WP32 + cp * 4];
            *(uint2*)(d)     = make_uint2(pk2(v.x, v.y), pk2(v.y, v.z));
            *(uint2*)(d + 2) = make_uint2(pk2(v.z, v.w), pk2(v.w, nx));
        }
    }
    __syncthreads();

    for (int cc = 0; cc < 4; ++cc) {
        int cb = cc * 32;

        // --- producer: interp own (i-tile, ch-half) -> Bl ---
#pragma unroll
        for (int k = 0; k < 3; ++k) {
            float v[8];
            float wa = wa_[k], wb = wb_[k];
            if (okw[k]) {
                int pos = a_[k] - wsod;
#pragma unroll
                for (int e = 0; e < 8; ++e) {
                    int row = hp * 16 + eh * 8 + e;
                    unsigned u = win32[row * WP32 + pos];
                    float lo = __uint_as_float(u << 16);
                    float hi = __uint_as_float(u & 0xffff0000u);
                    v[e] = wa * lo + wb * hi;
                }
            } else {
                int a = a_[k];
#pragma unroll
                for (int e = 0; e < 8; ++e) {
                    int c = cb + hp * 16 + eh * 8 + e;
                    const float* row = xb + (size_t)c * 4096;
                    f32x2u p2 = *(const f32x2u*)(row + a);
                    v[e] = wa * p2.x + wb * p2.y;
                }
            }
            bf16x8 Bv;
#pragma unroll
            for (int e = 0; e < 8; ++e) Bv[e] = (short)f2bf(v[e]);
            *(bf16x8*)&Bl[itp][k * 2 + hp][l * 8] = Bv;
        }

        // --- load + PACK next window early (12 regs live across MFMA) ---
        uint4 sp[3];
        if (cc < 3) {
#pragma unroll
            for (int it = 0; it < 3; ++it) {
                int idx = it * 512 + t;
                if (idx < 1280) {
                    int r = idx / 40, cp = idx - r * 40;
                    const float* row = xb + (size_t)(cb + 32 + r) * 4096;
                    int c0 = wsod + cp * 4;
                    float4 v = *(const float4*)(row + c0);
                    float nx = row[min(c0 + 4, 4095)];
                    sp[it] = make_uint4(pk2(v.x, v.y), pk2(v.y, v.z),
                                        pk2(v.z, v.w), pk2(v.w, nx));
                }
            }
        }

        // barrier #1: Bl writes + win reads complete (LDS-only wait)
        asm volatile("s_waitcnt lgkmcnt(0)" ::: "memory");
        __builtin_amdgcn_sched_barrier(0);
        __builtin_amdgcn_s_barrier();

        // --- consumer: A from L2 (short live range), B from Bl, 12 MFMAs ---
        __builtin_amdgcn_s_setprio(1);
#pragma unroll
        for (int tap = 0; tap < 3; ++tap) {
#pragma unroll
            for (int h = 0; h < 2; ++h) {
                bf16x8 A = Ag[(ot * 24 + tap * 8 + cc * 2 + h) * 64 + l];
#pragma unroll
                for (int j = 0; j < 2; ++j) {
                    bf16x8 Bv = *(const bf16x8*)&Bl[2 * ih + j][tap * 2 + h][l * 8];
                    acc[j] = __builtin_amdgcn_mfma_f32_32x32x16_bf16(A, Bv, acc[j], 0, 0, 0);
                }
            }
        }
        __builtin_amdgcn_s_setprio(0);

        // --- write packed window; barrier #2 closes phase ---
        if (cc < 3) {
#pragma unroll
            for (int it = 0; it < 3; ++it) {
                int idx = it * 512 + t;
                if (idx < 1280) {
                    int r = idx / 40, cp = idx - r * 40;
                    unsigned* d = &win32[r * WP32 + cp * 4];
                    *(uint2*)(d)     = make_uint2(sp[it].x, sp[it].y);
                    *(uint2*)(d + 2) = make_uint2(sp[it].z, sp[it].w);
                }
            }
            asm volatile("s_waitcnt lgkmcnt(0)" ::: "memory");
            __builtin_amdgcn_sched_barrier(0);
            __builtin_amdgcn_s_barrier();
        }
    }

    // C layout (32x32): col = lane&31, row = (reg&3) + 8*(reg>>2) + 4*(lane>>5)
    int rbase = 4 * eh;
#pragma unroll
    for (int j = 0; j < 2; ++j) {
        size_t ibase = (size_t)i0t + (2 * ih + j) * 32 + cl;
#pragma unroll
        for (int r = 0; r < 16; ++r) {
            int rowc = (r & 3) + 8 * (r >> 2) + rbase;
            int o = ot * 32 + rowc;
            out[((size_t)(b * 128 + o)) * 4096 + ibase] = acc[j][r];
        }
    }
}

extern "C" void kernel_launch(void* const* d_in, const int* in_sizes, int n_in,
                              void* d_out, int out_size, void* d_ws, size_t ws_size,
                              hipStream_t stream) {
    const float* x     = (const float*)d_in[0];
    const float* w_off = (const float*)d_in[1];
    const float* b_off = (const float*)d_in[2];
    const float* w_mod = (const float*)d_in[3];
    const float* b_mod = (const float*)d_in[4];
    const float* w_reg = (const float*)d_in[5];
    float* out = (float*)d_out;

    char* ws = (char*)d_ws;
    unsigned short* WrA = (unsigned short*)(ws);
    float* wT    = (float*)(ws + 98304);
    int*   addr2 = (int*)  (ws + 131072);
    float* wae   = (float*)(ws + 1703936);
    float* wbe   = (float*)(ws + 3276800);

    k_wra<<<206, 256, 0, stream>>>(w_reg, w_off, w_mod, WrA, wT);
    k_prep<<<dim3(32, 32), 512, 0, stream>>>(x, wT, b_off, b_mod,
                                             addr2, wae, wbe);
    k_fused<<<dim3(32, 32), 512, 0, stream>>>(WrA, x, addr2, wae, wbe, out);
}